// Round 1
// baseline (242.062 us; speedup 1.0000x reference)
//
#include <hip/hip_runtime.h>
#include <hip/hip_bf16.h>

#define B_  4
#define L_  4096
#define DM  1024
#define DH  128

// (1/sqrt(128)) * log2(e): softmax computed in exp2 domain (exact same function)
#define SC2 0.12752844f

typedef __bf16 bf16_t;
typedef __attribute__((ext_vector_type(8))) __bf16 bf16x8;
typedef __attribute__((ext_vector_type(4))) __bf16 bf16x4;
typedef __attribute__((ext_vector_type(4))) float f32x4;

#if __has_builtin(__builtin_amdgcn_exp2f)
#define EXP2F(x) __builtin_amdgcn_exp2f(x)
#else
#define EXP2F(x) exp2f(x)
#endif

__device__ __forceinline__ f32x4 mfma16(bf16x8 a, bf16x8 b, f32x4 c) {
    return __builtin_amdgcn_mfma_f32_16x16x32_bf16(a, b, c, 0, 0, 0);
}

// XOR swizzle on 16B slots within a row (row bytes must be 128 or 256)
__device__ __forceinline__ int swz(int row, int rowbytes, int colbyte) {
    int slot = colbyte >> 4;
    return row * rowbytes + (((slot ^ (row & 7)) << 4) | (colbyte & 15));
}

// ---------------------------------------------------------------------------
// Kernel A: projections  O[m,h] = X[m,:]·W[h,:] + bias[h]   (bt-GEMM)
// grid (128, 3), block 256.  BM=128, BN=128(=DH), BK=64
// ---------------------------------------------------------------------------
__global__ __launch_bounds__(256) void proj_kernel(
    const float* __restrict__ Xq, const float* __restrict__ Xk, const float* __restrict__ Xv,
    const float* __restrict__ Wq, const float* __restrict__ Wk, const float* __restrict__ Wv,
    const float* __restrict__ bq, const float* __restrict__ bk, const float* __restrict__ bv,
    bf16_t* __restrict__ Q, bf16_t* __restrict__ K, bf16_t* __restrict__ V)
{
    const int which = blockIdx.y;
    const float* X    = which == 0 ? Xq : (which == 1 ? Xk : Xv);
    const float* W    = which == 0 ? Wq : (which == 1 ? Wk : Wv);
    const float* bias = which == 0 ? bq : (which == 1 ? bk : bv);
    bf16_t*      O    = which == 0 ? Q  : (which == 1 ? K  : V);

    __shared__ bf16_t Alds[128 * 64];   // 16 KB, rows of 128 B, swizzled
    __shared__ bf16_t Wlds[128 * 64];   // 16 KB

    const int tid  = threadIdx.x;
    const int lane = tid & 63;
    const int wave = tid >> 6;
    const int wm = wave >> 1, wn = wave & 1;   // 2x2 wave grid, 64x64 each
    const int row0 = blockIdx.x * 128;

    f32x4 acc[4][4] = {};

    for (int kk = 0; kk < DM; kk += 64) {
        __syncthreads();
        // stage A tile [128][64] fp32 -> bf16 (8 float4 per thread)
        #pragma unroll
        for (int it = 0; it < 8; ++it) {
            int id = it * 256 + tid;
            int r = id >> 4, c4 = id & 15;
            float4 v = *(const float4*)&X[(size_t)(row0 + r) * DM + kk + c4 * 4];
            bf16x4 bv4;
            bv4[0] = (__bf16)v.x; bv4[1] = (__bf16)v.y; bv4[2] = (__bf16)v.z; bv4[3] = (__bf16)v.w;
            *(bf16x4*)((char*)Alds + swz(r, 128, c4 * 8)) = bv4;
        }
        // stage W tile [128][64]
        #pragma unroll
        for (int it = 0; it < 8; ++it) {
            int id = it * 256 + tid;
            int r = id >> 4, c4 = id & 15;
            float4 v = *(const float4*)&W[(size_t)r * DM + kk + c4 * 4];
            bf16x4 bv4;
            bv4[0] = (__bf16)v.x; bv4[1] = (__bf16)v.y; bv4[2] = (__bf16)v.z; bv4[3] = (__bf16)v.w;
            *(bf16x4*)((char*)Wlds + swz(r, 128, c4 * 8)) = bv4;
        }
        __syncthreads();
        #pragma unroll
        for (int ks = 0; ks < 2; ++ks) {
            bf16x8 af[4], bfr[4];
            #pragma unroll
            for (int mi = 0; mi < 4; ++mi) {
                int r = wm * 64 + mi * 16 + (lane & 15);
                af[mi] = *(const bf16x8*)((const char*)Alds + swz(r, 128, ks * 64 + (lane >> 4) * 16));
            }
            #pragma unroll
            for (int ni = 0; ni < 4; ++ni) {
                int r = wn * 64 + ni * 16 + (lane & 15);
                bfr[ni] = *(const bf16x8*)((const char*)Wlds + swz(r, 128, ks * 64 + (lane >> 4) * 16));
            }
            #pragma unroll
            for (int mi = 0; mi < 4; ++mi)
                #pragma unroll
                for (int ni = 0; ni < 4; ++ni)
                    acc[mi][ni] = mfma16(af[mi], bfr[ni], acc[mi][ni]);
        }
    }
    // epilogue: + bias, write bf16.  C/D: col=lane&15, row=(lane>>4)*4+j
    #pragma unroll
    for (int ni = 0; ni < 4; ++ni) {
        int h = wn * 64 + ni * 16 + (lane & 15);
        float bb = bias[h];
        #pragma unroll
        for (int mi = 0; mi < 4; ++mi)
            #pragma unroll
            for (int j = 0; j < 4; ++j) {
                int r = row0 + wm * 64 + mi * 16 + (lane >> 4) * 4 + j;
                O[(size_t)r * DH + h] = (__bf16)(acc[mi][ni][j] + bb);
            }
    }
}

// ---------------------------------------------------------------------------
// Kernel B: column-softmax stats.  Per block: 64 k-columns, loop all q.
// m2[b,k] = max_q (QK^T * SC2),  l[b,k] = sum_q exp2(s*SC2 - m2)
// grid (64, 4), block 256.
// ---------------------------------------------------------------------------
__global__ __launch_bounds__(256) void stats_kernel(
    const bf16_t* __restrict__ Q, const bf16_t* __restrict__ K,
    float* __restrict__ M2, float* __restrict__ Lsum)
{
    const int b  = blockIdx.y;
    const int k0 = blockIdx.x * 64;
    const int tid = threadIdx.x, lane = tid & 63, wave = tid >> 6;

    __shared__ bf16_t Klds[64 * 128];    // 16 KB, rows 256 B swizzled
    __shared__ bf16_t Qlds[256 * 128];   // 64 KB

    const bf16_t* Kb = K + ((size_t)b * L_ + k0) * DH;
    #pragma unroll
    for (int it = 0; it < 4; ++it) {
        int id = it * 256 + tid;
        int r = id >> 4, s = id & 15;
        bf16x8 x = *(const bf16x8*)&Kb[(size_t)r * DH + s * 8];
        *(bf16x8*)((char*)Klds + swz(r, 256, s * 16)) = x;
    }
    __syncthreads();
    // resident K fragments: [ni = 16-col block][d-slice]
    bf16x8 kfr[4][4];
    #pragma unroll
    for (int ni = 0; ni < 4; ++ni)
        #pragma unroll
        for (int ds = 0; ds < 4; ++ds) {
            int r = ni * 16 + (lane & 15);
            kfr[ni][ds] = *(const bf16x8*)((const char*)Klds + swz(r, 256, ds * 64 + (lane >> 4) * 16));
        }

    float mrun[4], lrun[4];
    #pragma unroll
    for (int ni = 0; ni < 4; ++ni) { mrun[ni] = -1e30f; lrun[ni] = 0.f; }

    const bf16_t* Qb = Q + (size_t)b * L_ * DH;
    for (int q0 = 0; q0 < L_; q0 += 256) {
        __syncthreads();
        #pragma unroll
        for (int it = 0; it < 16; ++it) {
            int id = it * 256 + tid;
            int r = id >> 4, s = id & 15;
            bf16x8 x = *(const bf16x8*)&Qb[(size_t)(q0 + r) * DH + s * 8];
            *(bf16x8*)((char*)Qlds + swz(r, 256, s * 16)) = x;
        }
        __syncthreads();
        // wave w: q rows [w*64, w*64+64), all 64 k
        f32x4 st[4][4] = {};
        #pragma unroll
        for (int mi = 0; mi < 4; ++mi)
            #pragma unroll
            for (int ds = 0; ds < 4; ++ds) {
                int r = wave * 64 + mi * 16 + (lane & 15);
                bf16x8 af = *(const bf16x8*)((const char*)Qlds + swz(r, 256, ds * 64 + (lane >> 4) * 16));
                #pragma unroll
                for (int ni = 0; ni < 4; ++ni)
                    st[mi][ni] = mfma16(af, kfr[ni][ds], st[mi][ni]);
            }
        // online per-column update (col k = lane&15 within ni block)
        #pragma unroll
        for (int ni = 0; ni < 4; ++ni) {
            float cm = -1e30f;
            #pragma unroll
            for (int mi = 0; mi < 4; ++mi)
                #pragma unroll
                for (int j = 0; j < 4; ++j) cm = fmaxf(cm, st[mi][ni][j]);
            cm *= SC2;
            cm = fmaxf(cm, __shfl_xor(cm, 16, 64));
            cm = fmaxf(cm, __shfl_xor(cm, 32, 64));
            float mnew = fmaxf(mrun[ni], cm);
            float p = 0.f;
            #pragma unroll
            for (int mi = 0; mi < 4; ++mi)
                #pragma unroll
                for (int j = 0; j < 4; ++j)
                    p += EXP2F(st[mi][ni][j] * SC2 - mnew);
            p += __shfl_xor(p, 16, 64);
            p += __shfl_xor(p, 32, 64);
            lrun[ni] = lrun[ni] * EXP2F(mrun[ni] - mnew) + p;
            mrun[ni] = mnew;
        }
    }
    // cross-wave combine (each wave covered a disjoint q subset)
    __syncthreads();
    float* redm = (float*)Klds;       // reuse: 4*64 floats
    float* redl = redm + 256;
    if (lane < 16) {
        #pragma unroll
        for (int ni = 0; ni < 4; ++ni) {
            redm[wave * 64 + ni * 16 + lane] = mrun[ni];
            redl[wave * 64 + ni * 16 + lane] = lrun[ni];
        }
    }
    __syncthreads();
    if (tid < 64) {
        float m0 = redm[tid], m1 = redm[64 + tid], m2v = redm[128 + tid], m3 = redm[192 + tid];
        float mt = fmaxf(fmaxf(m0, m1), fmaxf(m2v, m3));
        float lt = redl[tid]       * EXP2F(m0 - mt) + redl[64 + tid]  * EXP2F(m1 - mt)
                 + redl[128 + tid] * EXP2F(m2v - mt) + redl[192 + tid] * EXP2F(m3 - mt);
        M2[(size_t)b * L_ + k0 + tid]   = mt;
        Lsum[(size_t)b * L_ + k0 + tid] = lt;
    }
}

// ---------------------------------------------------------------------------
// Kernel C: VT[b][v][k] = V[b][k][v] / l[b][k]   (transpose + scale)
// grid (64, 2, 4), block 256
// ---------------------------------------------------------------------------
__global__ __launch_bounds__(256) void vt_kernel(
    const bf16_t* __restrict__ V, const float* __restrict__ Lsum, bf16_t* __restrict__ VT)
{
    const int b = blockIdx.z, v0 = blockIdx.y * 64, k0 = blockIdx.x * 64;
    __shared__ bf16_t tile[64][72];
    const int tid = threadIdx.x;
    const bf16_t* Vb = V + ((size_t)b * L_ + k0) * DH + v0;
    #pragma unroll
    for (int it = 0; it < 2; ++it) {
        int id = it * 256 + tid;
        int r = id >> 3, s = id & 7;
        bf16x8 x = *(const bf16x8*)&Vb[(size_t)r * DH + s * 8];
        *(bf16x8*)&tile[r][s * 8] = x;
    }
    __syncthreads();
    const int lane = tid & 63, wave = tid >> 6;
    float rl = 1.0f / Lsum[(size_t)b * L_ + k0 + lane];
    bf16_t* VTb = VT + ((size_t)b * DH + v0) * L_ + k0;
    #pragma unroll
    for (int i = 0; i < 16; ++i) {
        int v = wave * 16 + i;
        float x = (float)tile[lane][v];
        VTb[(size_t)v * L_ + lane] = (__bf16)(x * rl);
    }
}

// ---------------------------------------------------------------------------
// Kernel D: H[q,v] = sum_k exp2(s*SC2 - m2[k]) * VT[v][k]
// grid (64, 4), block 256 (4 waves).  q-block 64, k-chunks of 64.
// S^T = mfma(K, Q) so each lane's P values are k-contiguous (clean b64 write).
// ---------------------------------------------------------------------------
__global__ __launch_bounds__(256) void pv_kernel(
    const bf16_t* __restrict__ Q, const bf16_t* __restrict__ K,
    const bf16_t* __restrict__ VT, const float* __restrict__ M2,
    float* __restrict__ out)
{
    const int b = blockIdx.y;
    const int q0 = blockIdx.x * 64;
    const int tid = threadIdx.x, lane = tid & 63, wave = tid >> 6;

    __shared__ bf16_t Qlds[64 * 128];    // 16 KB
    __shared__ bf16_t Klds[64 * 128];    // 16 KB
    __shared__ bf16_t VTlds[128 * 64];   // 16 KB, rows 128 B
    __shared__ bf16_t Plds[64 * 64];     // 8 KB, rows 128 B

    const bf16_t* Qb = Q + ((size_t)b * L_ + q0) * DH;
    #pragma unroll
    for (int it = 0; it < 4; ++it) {
        int id = it * 256 + tid;
        int r = id >> 4, s = id & 15;
        bf16x8 x = *(const bf16x8*)&Qb[(size_t)r * DH + s * 8];
        *(bf16x8*)((char*)Qlds + swz(r, 256, s * 16)) = x;
    }
    __syncthreads();
    // resident Q fragments (B-operand of S^T): [ni = q 16-block][d-slice]
    bf16x8 qf[4][4];
    #pragma unroll
    for (int ni = 0; ni < 4; ++ni)
        #pragma unroll
        for (int ds = 0; ds < 4; ++ds) {
            int r = ni * 16 + (lane & 15);
            qf[ni][ds] = *(const bf16x8*)((const char*)Qlds + swz(r, 256, ds * 64 + (lane >> 4) * 16));
        }

    f32x4 acc[4][2] = {};
    const float*  m2b = M2 + (size_t)b * L_;
    const bf16_t* Kb  = K  + (size_t)b * L_ * DH;
    const bf16_t* VTb = VT + (size_t)b * DH * L_;

    for (int kc = 0; kc < L_; kc += 64) {
        __syncthreads();
        // stage K chunk [64 k][128 d]
        #pragma unroll
        for (int it = 0; it < 4; ++it) {
            int id = it * 256 + tid;
            int r = id >> 4, s = id & 15;
            bf16x8 x = *(const bf16x8*)&Kb[(size_t)(kc + r) * DH + s * 8];
            *(bf16x8*)((char*)Klds + swz(r, 256, s * 16)) = x;
        }
        // stage VT chunk [128 v][64 k]
        #pragma unroll
        for (int it = 0; it < 4; ++it) {
            int id = it * 256 + tid;
            int r = id >> 3, s = id & 7;
            bf16x8 x = *(const bf16x8*)&VTb[(size_t)r * L_ + kc + s * 8];
            *(bf16x8*)((char*)VTlds + swz(r, 128, s * 16)) = x;
        }
        __syncthreads();
        // S^T tile: wave w owns k rows [w*16, w*16+16), all 64 q
        f32x4 st[4] = {};
        #pragma unroll
        for (int ds = 0; ds < 4; ++ds) {
            int r = wave * 16 + (lane & 15);
            bf16x8 kf = *(const bf16x8*)((const char*)Klds + swz(r, 256, ds * 64 + (lane >> 4) * 16));
            #pragma unroll
            for (int ni = 0; ni < 4; ++ni)
                st[ni] = mfma16(kf, qf[ni][ds], st[ni]);
        }
        // P = exp2(s*SC2 - m2[k]), write bf16 to Plds (lane's 4 k contiguous)
        float4 mv = *(const float4*)&m2b[kc + wave * 16 + (lane >> 4) * 4];
        #pragma unroll
        for (int ni = 0; ni < 4; ++ni) {
            bf16x4 pk;
            pk[0] = (__bf16)EXP2F(st[ni][0] * SC2 - mv.x);
            pk[1] = (__bf16)EXP2F(st[ni][1] * SC2 - mv.y);
            pk[2] = (__bf16)EXP2F(st[ni][2] * SC2 - mv.z);
            pk[3] = (__bf16)EXP2F(st[ni][3] * SC2 - mv.w);
            int q = ni * 16 + (lane & 15);
            int colbyte = wave * 32 + (lane >> 4) * 8;
            *(bf16x4*)((char*)Plds + swz(q, 128, colbyte)) = pk;
        }
        __syncthreads();
        // PV: wave w owns v strip [w*32, w*32+32)
        #pragma unroll
        for (int ks = 0; ks < 2; ++ks) {
            bf16x8 pf[4], vf[2];
            #pragma unroll
            for (int mi = 0; mi < 4; ++mi) {
                int q = mi * 16 + (lane & 15);
                pf[mi] = *(const bf16x8*)((const char*)Plds + swz(q, 128, ks * 64 + (lane >> 4) * 16));
            }
            #pragma unroll
            for (int ni = 0; ni < 2; ++ni) {
                int v = wave * 32 + ni * 16 + (lane & 15);
                vf[ni] = *(const bf16x8*)((const char*)VTlds + swz(v, 128, ks * 64 + (lane >> 4) * 16));
            }
            #pragma unroll
            for (int mi = 0; mi < 4; ++mi)
                #pragma unroll
                for (int ni = 0; ni < 2; ++ni)
                    acc[mi][ni] = mfma16(pf[mi], vf[ni], acc[mi][ni]);
        }
    }
    // epilogue: fp32 out
    #pragma unroll
    for (int mi = 0; mi < 4; ++mi)
        #pragma unroll
        for (int ni = 0; ni < 2; ++ni)
            #pragma unroll
            for (int j = 0; j < 4; ++j) {
                int q = q0 + mi * 16 + (lane >> 4) * 4 + j;
                int v = wave * 32 + ni * 16 + (lane & 15);
                out[((size_t)b * L_ + q) * DH + v] = acc[mi][ni][j];
            }
}

// ---------------------------------------------------------------------------
extern "C" void kernel_launch(void* const* d_in, const int* in_sizes, int n_in,
                              void* d_out, int out_size, void* d_ws, size_t ws_size,
                              hipStream_t stream)
{
    const float* inq = (const float*)d_in[0];
    const float* ink = (const float*)d_in[1];
    const float* inv = (const float*)d_in[2];
    const float* Wq  = (const float*)d_in[3];
    const float* bq  = (const float*)d_in[4];
    const float* Wk  = (const float*)d_in[5];
    const float* bk  = (const float*)d_in[6];
    const float* Wv  = (const float*)d_in[7];
    const float* bv  = (const float*)d_in[8];
    float* out = (float*)d_out;

    const size_t nQKV = (size_t)B_ * L_ * DH;   // 2,097,152 elements
    char* ws = (char*)d_ws;
    bf16_t* Q  = (bf16_t*)ws;
    bf16_t* K  = Q + nQKV;
    bf16_t* V  = K + nQKV;
    bf16_t* VT = V + nQKV;
    float*  M2   = (float*)(VT + nQKV);
    float*  Lsum = M2 + (size_t)B_ * L_;

    proj_kernel<<<dim3(128, 3), 256, 0, stream>>>(inq, ink, inv, Wq, Wk, Wv, bq, bk, bv, Q, K, V);
    stats_kernel<<<dim3(L_ / 64, B_), 256, 0, stream>>>(Q, K, M2, Lsum);
    vt_kernel<<<dim3(L_ / 64, DH / 64, B_), 256, 0, stream>>>(V, Lsum, VT);
    pv_kernel<<<dim3(L_ / 64, B_), 256, 0, stream>>>(Q, K, VT, M2, out);
}

// Round 2
// 184.098 us; speedup vs baseline: 1.3149x; 1.3149x over previous
//
#include <hip/hip_runtime.h>
#include <hip/hip_bf16.h>

#define B_  4
#define L_  4096
#define DM  1024
#define DH  128
#define KS  4     // k-split for pv
#define QS  4     // q-split for stats

// (1/sqrt(128)) * log2(e): softmax computed in exp2 domain (exact same function)
#define SC2 0.12752844f

typedef __bf16 bf16_t;
typedef __attribute__((ext_vector_type(8))) __bf16 bf16x8;
typedef __attribute__((ext_vector_type(4))) __bf16 bf16x4;
typedef __attribute__((ext_vector_type(4))) float f32x4;

#if __has_builtin(__builtin_amdgcn_exp2f)
#define EXP2F(x) __builtin_amdgcn_exp2f(x)
#else
#define EXP2F(x) exp2f(x)
#endif

__device__ __forceinline__ f32x4 mfma16(bf16x8 a, bf16x8 b, f32x4 c) {
    return __builtin_amdgcn_mfma_f32_16x16x32_bf16(a, b, c, 0, 0, 0);
}

// XOR swizzle on 16B slots within a row (row bytes must be 128 or 256)
__device__ __forceinline__ int swz(int row, int rowbytes, int colbyte) {
    int slot = colbyte >> 4;
    return row * rowbytes + (((slot ^ (row & 7)) << 4) | (colbyte & 15));
}

// ---------------------------------------------------------------------------
// Kernel A: projections  O[m,h] = X[m,:]·W[h,:] + bias[h]   (bt-GEMM)
// grid (256, 3), block 256.  BM=64, BN=128(=DH), BK=64.  24KB LDS -> high occ.
// ---------------------------------------------------------------------------
__global__ __launch_bounds__(256) void proj_kernel(
    const float* __restrict__ Xq, const float* __restrict__ Xk, const float* __restrict__ Xv,
    const float* __restrict__ Wq, const float* __restrict__ Wk, const float* __restrict__ Wv,
    const float* __restrict__ bq, const float* __restrict__ bk, const float* __restrict__ bv,
    bf16_t* __restrict__ Q, bf16_t* __restrict__ K, bf16_t* __restrict__ V)
{
    const int which = blockIdx.y;
    const float* X    = which == 0 ? Xq : (which == 1 ? Xk : Xv);
    const float* W    = which == 0 ? Wq : (which == 1 ? Wk : Wv);
    const float* bias = which == 0 ? bq : (which == 1 ? bk : bv);
    bf16_t*      O    = which == 0 ? Q  : (which == 1 ? K  : V);

    __shared__ bf16_t Alds[64 * 64];    // 8 KB, rows 128 B, swizzled
    __shared__ bf16_t Wlds[128 * 64];   // 16 KB

    const int tid  = threadIdx.x;
    const int lane = tid & 63;
    const int wave = tid >> 6;
    const int wm = wave >> 1, wn = wave & 1;   // 2x2 wave grid: 32q x 64h each
    const int row0 = blockIdx.x * 64;

    f32x4 acc[2][4] = {};

    for (int kk = 0; kk < DM; kk += 64) {
        __syncthreads();
        // stage A tile [64][64] fp32 -> bf16 (4 float4 per thread)
        #pragma unroll
        for (int it = 0; it < 4; ++it) {
            int id = it * 256 + tid;
            int r = id >> 4, c4 = id & 15;
            float4 v = *(const float4*)&X[(size_t)(row0 + r) * DM + kk + c4 * 4];
            bf16x4 bv4;
            bv4[0] = (__bf16)v.x; bv4[1] = (__bf16)v.y; bv4[2] = (__bf16)v.z; bv4[3] = (__bf16)v.w;
            *(bf16x4*)((char*)Alds + swz(r, 128, c4 * 8)) = bv4;
        }
        // stage W tile [128][64]
        #pragma unroll
        for (int it = 0; it < 8; ++it) {
            int id = it * 256 + tid;
            int r = id >> 4, c4 = id & 15;
            float4 v = *(const float4*)&W[(size_t)r * DM + kk + c4 * 4];
            bf16x4 bv4;
            bv4[0] = (__bf16)v.x; bv4[1] = (__bf16)v.y; bv4[2] = (__bf16)v.z; bv4[3] = (__bf16)v.w;
            *(bf16x4*)((char*)Wlds + swz(r, 128, c4 * 8)) = bv4;
        }
        __syncthreads();
        #pragma unroll
        for (int ks = 0; ks < 2; ++ks) {
            bf16x8 af[2], bfr[4];
            #pragma unroll
            for (int mi = 0; mi < 2; ++mi) {
                int r = wm * 32 + mi * 16 + (lane & 15);
                af[mi] = *(const bf16x8*)((const char*)Alds + swz(r, 128, ks * 64 + (lane >> 4) * 16));
            }
            #pragma unroll
            for (int ni = 0; ni < 4; ++ni) {
                int r = wn * 64 + ni * 16 + (lane & 15);
                bfr[ni] = *(const bf16x8*)((const char*)Wlds + swz(r, 128, ks * 64 + (lane >> 4) * 16));
            }
            #pragma unroll
            for (int mi = 0; mi < 2; ++mi)
                #pragma unroll
                for (int ni = 0; ni < 4; ++ni)
                    acc[mi][ni] = mfma16(af[mi], bfr[ni], acc[mi][ni]);
        }
    }
    // epilogue: + bias, write bf16.  C/D: col=lane&15, row=(lane>>4)*4+j
    #pragma unroll
    for (int ni = 0; ni < 4; ++ni) {
        int h = wn * 64 + ni * 16 + (lane & 15);
        float bb = bias[h];
        #pragma unroll
        for (int mi = 0; mi < 2; ++mi)
            #pragma unroll
            for (int j = 0; j < 4; ++j) {
                int r = row0 + wm * 32 + mi * 16 + (lane >> 4) * 4 + j;
                O[(size_t)r * DH + h] = (__bf16)(acc[mi][ni][j] + bb);
            }
    }
}

// ---------------------------------------------------------------------------
// Kernel B: column-softmax partial stats over a q-range of L/QS.
// grid (64, B, QS), block 256.  Per block: 64 k-columns, 1024 q rows.
// ---------------------------------------------------------------------------
__global__ __launch_bounds__(256) void stats_kernel(
    const bf16_t* __restrict__ Q, const bf16_t* __restrict__ K,
    float* __restrict__ Mpart, float* __restrict__ Lpart)
{
    const int b  = blockIdx.y;
    const int k0 = blockIdx.x * 64;
    const int qs = blockIdx.z;
    const int tid = threadIdx.x, lane = tid & 63, wave = tid >> 6;

    __shared__ bf16_t Klds[64 * 128];    // 16 KB, rows 256 B swizzled
    __shared__ bf16_t Qlds[128 * 128];   // 32 KB

    const bf16_t* Kb = K + ((size_t)b * L_ + k0) * DH;
    #pragma unroll
    for (int it = 0; it < 4; ++it) {
        int id = it * 256 + tid;
        int r = id >> 4, s = id & 15;
        bf16x8 x = *(const bf16x8*)&Kb[(size_t)r * DH + s * 8];
        *(bf16x8*)((char*)Klds + swz(r, 256, s * 16)) = x;
    }
    __syncthreads();
    // resident K fragments: [ni = 16-col block][d-slice]
    bf16x8 kfr[4][4];
    #pragma unroll
    for (int ni = 0; ni < 4; ++ni)
        #pragma unroll
        for (int ds = 0; ds < 4; ++ds) {
            int r = ni * 16 + (lane & 15);
            kfr[ni][ds] = *(const bf16x8*)((const char*)Klds + swz(r, 256, ds * 64 + (lane >> 4) * 16));
        }

    float mrun[4], lrun[4];
    #pragma unroll
    for (int ni = 0; ni < 4; ++ni) { mrun[ni] = -1e30f; lrun[ni] = 0.f; }

    const bf16_t* Qb = Q + (size_t)b * L_ * DH;
    const int qbase = qs * (L_ / QS);
    for (int q0 = qbase; q0 < qbase + L_ / QS; q0 += 128) {
        __syncthreads();
        #pragma unroll
        for (int it = 0; it < 8; ++it) {
            int id = it * 256 + tid;
            int r = id >> 4, s = id & 15;
            bf16x8 x = *(const bf16x8*)&Qb[(size_t)(q0 + r) * DH + s * 8];
            *(bf16x8*)((char*)Qlds + swz(r, 256, s * 16)) = x;
        }
        __syncthreads();
        // wave w: q rows [w*32, w*32+32), all 64 k
        f32x4 st[2][4] = {};
        #pragma unroll
        for (int mi = 0; mi < 2; ++mi)
            #pragma unroll
            for (int ds = 0; ds < 4; ++ds) {
                int r = wave * 32 + mi * 16 + (lane & 15);
                bf16x8 af = *(const bf16x8*)((const char*)Qlds + swz(r, 256, ds * 64 + (lane >> 4) * 16));
                #pragma unroll
                for (int ni = 0; ni < 4; ++ni)
                    st[mi][ni] = mfma16(af, kfr[ni][ds], st[mi][ni]);
            }
        // online per-column update (col k = lane&15 within ni block)
        #pragma unroll
        for (int ni = 0; ni < 4; ++ni) {
            float cm = -1e30f;
            #pragma unroll
            for (int mi = 0; mi < 2; ++mi)
                #pragma unroll
                for (int j = 0; j < 4; ++j) cm = fmaxf(cm, st[mi][ni][j]);
            cm *= SC2;
            cm = fmaxf(cm, __shfl_xor(cm, 16, 64));
            cm = fmaxf(cm, __shfl_xor(cm, 32, 64));
            float mnew = fmaxf(mrun[ni], cm);
            float p = 0.f;
            #pragma unroll
            for (int mi = 0; mi < 2; ++mi)
                #pragma unroll
                for (int j = 0; j < 4; ++j)
                    p += EXP2F(st[mi][ni][j] * SC2 - mnew);
            p += __shfl_xor(p, 16, 64);
            p += __shfl_xor(p, 32, 64);
            lrun[ni] = lrun[ni] * EXP2F(mrun[ni] - mnew) + p;
            mrun[ni] = mnew;
        }
    }
    // cross-wave combine (each wave covered a disjoint q subset)
    __syncthreads();
    float* redm = (float*)Klds;       // reuse: 4*64 floats
    float* redl = redm + 256;
    if (lane < 16) {
        #pragma unroll
        for (int ni = 0; ni < 4; ++ni) {
            redm[wave * 64 + ni * 16 + lane] = mrun[ni];
            redl[wave * 64 + ni * 16 + lane] = lrun[ni];
        }
    }
    __syncthreads();
    if (tid < 64) {
        float m0 = redm[tid], m1 = redm[64 + tid], m2v = redm[128 + tid], m3 = redm[192 + tid];
        float mt = fmaxf(fmaxf(m0, m1), fmaxf(m2v, m3));
        float lt = redl[tid]       * EXP2F(m0 - mt) + redl[64 + tid]  * EXP2F(m1 - mt)
                 + redl[128 + tid] * EXP2F(m2v - mt) + redl[192 + tid] * EXP2F(m3 - mt);
        Mpart[((size_t)qs * B_ + b) * L_ + k0 + tid] = mt;
        Lpart[((size_t)qs * B_ + b) * L_ + k0 + tid] = lt;
    }
}

// ---------------------------------------------------------------------------
// Kernel B2: combine QS partial stats -> M2, Lsum.  grid (B*L/256), block 256
// ---------------------------------------------------------------------------
__global__ __launch_bounds__(256) void comb_kernel(
    const float* __restrict__ Mpart, const float* __restrict__ Lpart,
    float* __restrict__ M2, float* __restrict__ Lsum)
{
    const size_t i = (size_t)blockIdx.x * 256 + threadIdx.x;
    const size_t N = (size_t)B_ * L_;
    float m = -1e30f;
    #pragma unroll
    for (int qs = 0; qs < QS; ++qs) m = fmaxf(m, Mpart[qs * N + i]);
    float l = 0.f;
    #pragma unroll
    for (int qs = 0; qs < QS; ++qs) l += Lpart[qs * N + i] * EXP2F(Mpart[qs * N + i] - m);
    M2[i] = m;
    Lsum[i] = l;
}

// ---------------------------------------------------------------------------
// Kernel C: VT[b][v][k] = V[b][k][v] / l[b][k]   (transpose + scale)
// grid (64, 2, 4), block 256
// ---------------------------------------------------------------------------
__global__ __launch_bounds__(256) void vt_kernel(
    const bf16_t* __restrict__ V, const float* __restrict__ Lsum, bf16_t* __restrict__ VT)
{
    const int b = blockIdx.z, v0 = blockIdx.y * 64, k0 = blockIdx.x * 64;
    __shared__ bf16_t tile[64][72];
    const int tid = threadIdx.x;
    const bf16_t* Vb = V + ((size_t)b * L_ + k0) * DH + v0;
    #pragma unroll
    for (int it = 0; it < 2; ++it) {
        int id = it * 256 + tid;
        int r = id >> 3, s = id & 7;
        bf16x8 x = *(const bf16x8*)&Vb[(size_t)r * DH + s * 8];
        *(bf16x8*)&tile[r][s * 8] = x;
    }
    __syncthreads();
    const int lane = tid & 63, wave = tid >> 6;
    float rl = 1.0f / Lsum[(size_t)b * L_ + k0 + lane];
    bf16_t* VTb = VT + ((size_t)b * DH + v0) * L_ + k0;
    #pragma unroll
    for (int i = 0; i < 16; ++i) {
        int v = wave * 16 + i;
        float x = (float)tile[lane][v];
        VTb[(size_t)v * L_ + lane] = (__bf16)(x * rl);
    }
}

// ---------------------------------------------------------------------------
// Kernel D: H[q,v] += sum_{k in range} exp2(s*SC2 - m2[k]) * VT[v][k]
// grid (64, B, KS), block 256 (4 waves).  q-block 64, k-range L/KS, chunks 64.
// Partial k-sums are additive (1/l folded into VT) -> fp32 atomicAdd to out.
// ---------------------------------------------------------------------------
__global__ __launch_bounds__(256) void pv_kernel(
    const bf16_t* __restrict__ Q, const bf16_t* __restrict__ K,
    const bf16_t* __restrict__ VT, const float* __restrict__ M2,
    float* __restrict__ out)
{
    const int b = blockIdx.y;
    const int q0 = blockIdx.x * 64;
    const int tid = threadIdx.x, lane = tid & 63, wave = tid >> 6;

    __shared__ bf16_t QPlds[64 * 128];   // 16 KB: Q staging, then P tile (first 8 KB)
    __shared__ bf16_t Klds[64 * 128];    // 16 KB
    __shared__ bf16_t VTlds[128 * 64];   // 16 KB, rows 128 B

    const bf16_t* Qb = Q + ((size_t)b * L_ + q0) * DH;
    #pragma unroll
    for (int it = 0; it < 4; ++it) {
        int id = it * 256 + tid;
        int r = id >> 4, s = id & 15;
        bf16x8 x = *(const bf16x8*)&Qb[(size_t)r * DH + s * 8];
        *(bf16x8*)((char*)QPlds + swz(r, 256, s * 16)) = x;
    }
    __syncthreads();
    // resident Q fragments (B-operand of S^T): [ni = q 16-block][d-slice]
    bf16x8 qf[4][4];
    #pragma unroll
    for (int ni = 0; ni < 4; ++ni)
        #pragma unroll
        for (int ds = 0; ds < 4; ++ds) {
            int r = ni * 16 + (lane & 15);
            qf[ni][ds] = *(const bf16x8*)((const char*)QPlds + swz(r, 256, ds * 64 + (lane >> 4) * 16));
        }

    f32x4 acc[4][2] = {};
    const float*  m2b = M2 + (size_t)b * L_;
    const bf16_t* Kb  = K  + (size_t)b * L_ * DH;
    const bf16_t* VTb = VT + (size_t)b * DH * L_;
    bf16_t* Plds = QPlds;                // alias: safe after qf loads + barrier

    const int kbase = blockIdx.z * (L_ / KS);
    for (int kc = kbase; kc < kbase + L_ / KS; kc += 64) {
        __syncthreads();
        // stage K chunk [64 k][128 d]
        #pragma unroll
        for (int it = 0; it < 4; ++it) {
            int id = it * 256 + tid;
            int r = id >> 4, s = id & 15;
            bf16x8 x = *(const bf16x8*)&Kb[(size_t)(kc + r) * DH + s * 8];
            *(bf16x8*)((char*)Klds + swz(r, 256, s * 16)) = x;
        }
        // stage VT chunk [128 v][64 k]
        #pragma unroll
        for (int it = 0; it < 4; ++it) {
            int id = it * 256 + tid;
            int r = id >> 3, s = id & 7;
            bf16x8 x = *(const bf16x8*)&VTb[(size_t)r * L_ + kc + s * 8];
            *(bf16x8*)((char*)VTlds + swz(r, 128, s * 16)) = x;
        }
        __syncthreads();
        // S^T tile: wave w owns k rows [w*16, w*16+16), all 64 q
        f32x4 st[4] = {};
        #pragma unroll
        for (int ds = 0; ds < 4; ++ds) {
            int r = wave * 16 + (lane & 15);
            bf16x8 kf = *(const bf16x8*)((const char*)Klds + swz(r, 256, ds * 64 + (lane >> 4) * 16));
            #pragma unroll
            for (int ni = 0; ni < 4; ++ni)
                st[ni] = mfma16(kf, qf[ni][ds], st[ni]);
        }
        // P = exp2(s*SC2 - m2[k]), write bf16 to Plds (lane's 4 k contiguous)
        float4 mv = *(const float4*)&m2b[kc + wave * 16 + (lane >> 4) * 4];
        #pragma unroll
        for (int ni = 0; ni < 4; ++ni) {
            bf16x4 pk;
            pk[0] = (__bf16)EXP2F(st[ni][0] * SC2 - mv.x);
            pk[1] = (__bf16)EXP2F(st[ni][1] * SC2 - mv.y);
            pk[2] = (__bf16)EXP2F(st[ni][2] * SC2 - mv.z);
            pk[3] = (__bf16)EXP2F(st[ni][3] * SC2 - mv.w);
            int q = ni * 16 + (lane & 15);
            int colbyte = wave * 32 + (lane >> 4) * 8;
            *(bf16x4*)((char*)Plds + swz(q, 128, colbyte)) = pk;
        }
        __syncthreads();
        // PV: wave w owns v strip [w*32, w*32+32)
        #pragma unroll
        for (int ks = 0; ks < 2; ++ks) {
            bf16x8 pf[4], vf[2];
            #pragma unroll
            for (int mi = 0; mi < 4; ++mi) {
                int q = mi * 16 + (lane & 15);
                pf[mi] = *(const bf16x8*)((const char*)Plds + swz(q, 128, ks * 64 + (lane >> 4) * 16));
            }
            #pragma unroll
            for (int ni = 0; ni < 2; ++ni) {
                int v = wave * 32 + ni * 16 + (lane & 15);
                vf[ni] = *(const bf16x8*)((const char*)VTlds + swz(v, 128, ks * 64 + (lane >> 4) * 16));
            }
            #pragma unroll
            for (int mi = 0; mi < 4; ++mi)
                #pragma unroll
                for (int ni = 0; ni < 2; ++ni)
                    acc[mi][ni] = mfma16(pf[mi], vf[ni], acc[mi][ni]);
        }
    }
    // epilogue: fp32 atomic accumulate (KS blocks contribute per output)
    #pragma unroll
    for (int mi = 0; mi < 4; ++mi)
        #pragma unroll
        for (int ni = 0; ni < 2; ++ni)
            #pragma unroll
            for (int j = 0; j < 4; ++j) {
                int q = q0 + mi * 16 + (lane >> 4) * 4 + j;
                int v = wave * 32 + ni * 16 + (lane & 15);
                atomicAdd(&out[((size_t)b * L_ + q) * DH + v], acc[mi][ni][j]);
            }
}

// ---------------------------------------------------------------------------
extern "C" void kernel_launch(void* const* d_in, const int* in_sizes, int n_in,
                              void* d_out, int out_size, void* d_ws, size_t ws_size,
                              hipStream_t stream)
{
    const float* inq = (const float*)d_in[0];
    const float* ink = (const float*)d_in[1];
    const float* inv = (const float*)d_in[2];
    const float* Wq  = (const float*)d_in[3];
    const float* bq  = (const float*)d_in[4];
    const float* Wk  = (const float*)d_in[5];
    const float* bk  = (const float*)d_in[6];
    const float* Wv  = (const float*)d_in[7];
    const float* bv  = (const float*)d_in[8];
    float* out = (float*)d_out;

    const size_t nQKV = (size_t)B_ * L_ * DH;   // 2,097,152 elements
    const size_t nBL  = (size_t)B_ * L_;
    char* ws = (char*)d_ws;
    bf16_t* Q  = (bf16_t*)ws;
    bf16_t* K  = Q + nQKV;
    bf16_t* V  = K + nQKV;
    bf16_t* VT = V + nQKV;
    float*  M2    = (float*)(VT + nQKV);
    float*  Lsum  = M2 + nBL;
    float*  Mpart = Lsum + nBL;          // QS * B*L
    float*  Lpart = Mpart + QS * nBL;    // QS * B*L

    hipMemsetAsync(out, 0, nQKV * sizeof(float), stream);
    proj_kernel<<<dim3(256, 3), 256, 0, stream>>>(inq, ink, inv, Wq, Wk, Wv, bq, bk, bv, Q, K, V);
    stats_kernel<<<dim3(L_ / 64, B_, QS), 256, 0, stream>>>(Q, K, Mpart, Lpart);
    comb_kernel<<<dim3(nBL / 256), 256, 0, stream>>>(Mpart, Lpart, M2, Lsum);
    vt_kernel<<<dim3(L_ / 64, DH / 64, B_), 256, 0, stream>>>(V, Lsum, VT);
    pv_kernel<<<dim3(L_ / 64, B_, KS), 256, 0, stream>>>(Q, K, VT, M2, out);
}

// Round 3
// 180.870 us; speedup vs baseline: 1.3383x; 1.0178x over previous
//
#include <hip/hip_runtime.h>
#include <hip/hip_bf16.h>

#define B_  4
#define L_  4096
#define DM  1024
#define DH  128
#define KS  4     // k-split for pv
#define QS  4     // q-split for stats

// (1/sqrt(128)) * log2(e): softmax computed in exp2 domain (exact same function)
#define SC2 0.12752844f

typedef __bf16 bf16_t;
typedef __attribute__((ext_vector_type(8))) __bf16 bf16x8;
typedef __attribute__((ext_vector_type(4))) __bf16 bf16x4;
typedef __attribute__((ext_vector_type(4))) float f32x4;

#if __has_builtin(__builtin_amdgcn_exp2f)
#define EXP2F(x) __builtin_amdgcn_exp2f(x)
#else
#define EXP2F(x) exp2f(x)
#endif

__device__ __forceinline__ f32x4 mfma16(bf16x8 a, bf16x8 b, f32x4 c) {
    return __builtin_amdgcn_mfma_f32_16x16x32_bf16(a, b, c, 0, 0, 0);
}

// XOR swizzle on 16B slots within a row (row bytes must be 128 or 256)
__device__ __forceinline__ int swz(int row, int rowbytes, int colbyte) {
    int slot = colbyte >> 4;
    return row * rowbytes + (((slot ^ (row & 7)) << 4) | (colbyte & 15));
}

// async global->LDS, 16 B per lane. lds base must be wave-uniform; HW adds lane*16.
__device__ __forceinline__ void gload_lds16(const void* g, void* l) {
    __builtin_amdgcn_global_load_lds((const __attribute__((address_space(1))) void*)g,
                                     (__attribute__((address_space(3))) void*)l, 16, 0, 0);
}

// ---------------------------------------------------------------------------
// Kernel A0: W fp32 -> bf16 once.  Wb layout [3][DH][DM].  grid 192, block 256
// ---------------------------------------------------------------------------
__global__ __launch_bounds__(256) void wcvt_kernel(
    const float* __restrict__ Wq, const float* __restrict__ Wk, const float* __restrict__ Wv,
    bf16_t* __restrict__ Wb)
{
    int idx = (blockIdx.x * 256 + threadIdx.x) * 8;    // into [3][131072]
    int which = idx >> 17;
    int rem = idx & 131071;
    const float* W = which == 0 ? Wq : (which == 1 ? Wk : Wv);
    float4 a = *(const float4*)&W[rem];
    float4 b = *(const float4*)&W[rem + 4];
    bf16x8 o;
    o[0] = (__bf16)a.x; o[1] = (__bf16)a.y; o[2] = (__bf16)a.z; o[3] = (__bf16)a.w;
    o[4] = (__bf16)b.x; o[5] = (__bf16)b.y; o[6] = (__bf16)b.z; o[7] = (__bf16)b.w;
    *(bf16x8*)&Wb[idx] = o;
}

// ---------------------------------------------------------------------------
// Kernel A: projections  O[m,h] = X[m,:]·W[h,:] + bias[h]
// grid (256, 3), block 256.  BM=64, BN=128(=DH), BK=64.
// X staged fp32 via global_load_lds (cvt to bf16 on fragment read); W staged
// bf16 via global_load_lds.  Linear LDS dest + inverse-swizzled global source
// + swizzled read (slot ^= row&7).
// ---------------------------------------------------------------------------
__global__ __launch_bounds__(256) void proj_kernel(
    const float* __restrict__ Xq, const float* __restrict__ Xk, const float* __restrict__ Xv,
    const bf16_t* __restrict__ Wb,
    const float* __restrict__ bq, const float* __restrict__ bk, const float* __restrict__ bv,
    bf16_t* __restrict__ Q, bf16_t* __restrict__ K, bf16_t* __restrict__ V)
{
    const int which = blockIdx.y;
    const float* X    = which == 0 ? Xq : (which == 1 ? Xk : Xv);
    const float* bias = which == 0 ? bq : (which == 1 ? bk : bv);
    bf16_t*      O    = which == 0 ? Q  : (which == 1 ? K  : V);
    const bf16_t* Wm  = Wb + (size_t)which * DH * DM;

    __shared__ float  Xlds[64 * 64];    // 16 KB, rows 256 B = 16 slots
    __shared__ bf16_t Wlds[128 * 64];   // 16 KB, rows 128 B = 8 slots

    const int tid  = threadIdx.x;
    const int lane = tid & 63;
    const int wave = tid >> 6;
    const int wm = wave >> 1, wn = wave & 1;   // 2x2 wave grid: 32m x 64h each
    const int row0 = blockIdx.x * 64;

    f32x4 acc[2][4] = {};

    for (int kk = 0; kk < DM; kk += 64) {
        __syncthreads();
        // stage X [64 rows][64 f32]: 4 issues/thread, 1024 B per wave-issue (4 rows)
        #pragma unroll
        for (int j = 0; j < 4; ++j) {
            int c = wave * 4 + j;
            int r = c * 4 + (lane >> 4);
            int s = lane & 15;
            gload_lds16(&X[(size_t)(row0 + r) * DM + kk + ((s ^ (r & 7)) << 2)],
                        (char*)Xlds + c * 1024);
        }
        // stage W [128 rows][64 bf16]: 4 issues/thread, 1024 B per wave-issue (8 rows)
        #pragma unroll
        for (int j = 0; j < 4; ++j) {
            int c = wave * 4 + j;
            int r = c * 8 + (lane >> 3);
            int s = lane & 7;
            gload_lds16(&Wm[(size_t)r * DM + kk + ((s ^ (r & 7)) << 3)],
                        (char*)Wlds + c * 1024);
        }
        __syncthreads();
        #pragma unroll
        for (int ks = 0; ks < 2; ++ks) {
            bf16x8 af[2], bfr[4];
            #pragma unroll
            for (int mi = 0; mi < 2; ++mi) {
                int r = wm * 32 + mi * 16 + (lane & 15);
                int rx = r & 7;
                int s0 = ks * 8 + (lane >> 4) * 2;
                float4 x0 = *(const float4*)&Xlds[r * 64 + ((s0 ^ rx) << 2)];
                float4 x1 = *(const float4*)&Xlds[r * 64 + (((s0 + 1) ^ rx) << 2)];
                bf16x8 a;
                a[0] = (__bf16)x0.x; a[1] = (__bf16)x0.y; a[2] = (__bf16)x0.z; a[3] = (__bf16)x0.w;
                a[4] = (__bf16)x1.x; a[5] = (__bf16)x1.y; a[6] = (__bf16)x1.z; a[7] = (__bf16)x1.w;
                af[mi] = a;
            }
            #pragma unroll
            for (int ni = 0; ni < 4; ++ni) {
                int r = wn * 64 + ni * 16 + (lane & 15);
                int t = ks * 4 + (lane >> 4);
                bfr[ni] = *(const bf16x8*)((const char*)Wlds + r * 128 + ((t ^ (r & 7)) << 4));
            }
            #pragma unroll
            for (int mi = 0; mi < 2; ++mi)
                #pragma unroll
                for (int ni = 0; ni < 4; ++ni)
                    acc[mi][ni] = mfma16(af[mi], bfr[ni], acc[mi][ni]);
        }
    }
    // epilogue: + bias, write bf16.  C/D: col=lane&15, row=(lane>>4)*4+j
    #pragma unroll
    for (int ni = 0; ni < 4; ++ni) {
        int h = wn * 64 + ni * 16 + (lane & 15);
        float bb = bias[h];
        #pragma unroll
        for (int mi = 0; mi < 2; ++mi)
            #pragma unroll
            for (int j = 0; j < 4; ++j) {
                int r = row0 + wm * 32 + mi * 16 + (lane >> 4) * 4 + j;
                O[(size_t)r * DH + h] = (__bf16)(acc[mi][ni][j] + bb);
            }
    }
}

// ---------------------------------------------------------------------------
// Kernel B: column-softmax partial stats over a q-range of L/QS.
// grid (64, B, QS), block 256.  Per block: 64 k-columns, 1024 q rows.
// ---------------------------------------------------------------------------
__global__ __launch_bounds__(256) void stats_kernel(
    const bf16_t* __restrict__ Q, const bf16_t* __restrict__ K,
    float* __restrict__ Mpart, float* __restrict__ Lpart)
{
    const int b  = blockIdx.y;
    const int k0 = blockIdx.x * 64;
    const int qs = blockIdx.z;
    const int tid = threadIdx.x, lane = tid & 63, wave = tid >> 6;

    __shared__ bf16_t Klds[64 * 128];    // 16 KB, rows 256 B swizzled
    __shared__ bf16_t Qlds[128 * 128];   // 32 KB

    const bf16_t* Kb = K + ((size_t)b * L_ + k0) * DH;
    #pragma unroll
    for (int it = 0; it < 4; ++it) {
        int id = it * 256 + tid;
        int r = id >> 4, s = id & 15;
        bf16x8 x = *(const bf16x8*)&Kb[(size_t)r * DH + s * 8];
        *(bf16x8*)((char*)Klds + swz(r, 256, s * 16)) = x;
    }
    __syncthreads();
    // resident K fragments: [ni = 16-col block][d-slice]
    bf16x8 kfr[4][4];
    #pragma unroll
    for (int ni = 0; ni < 4; ++ni)
        #pragma unroll
        for (int ds = 0; ds < 4; ++ds) {
            int r = ni * 16 + (lane & 15);
            kfr[ni][ds] = *(const bf16x8*)((const char*)Klds + swz(r, 256, ds * 64 + (lane >> 4) * 16));
        }

    float mrun[4], lrun[4];
    #pragma unroll
    for (int ni = 0; ni < 4; ++ni) { mrun[ni] = -1e30f; lrun[ni] = 0.f; }

    const bf16_t* Qb = Q + (size_t)b * L_ * DH;
    const int qbase = qs * (L_ / QS);
    for (int q0 = qbase; q0 < qbase + L_ / QS; q0 += 128) {
        __syncthreads();
        #pragma unroll
        for (int it = 0; it < 8; ++it) {
            int id = it * 256 + tid;
            int r = id >> 4, s = id & 15;
            bf16x8 x = *(const bf16x8*)&Qb[(size_t)(q0 + r) * DH + s * 8];
            *(bf16x8*)((char*)Qlds + swz(r, 256, s * 16)) = x;
        }
        __syncthreads();
        // wave w: q rows [w*32, w*32+32), all 64 k
        f32x4 st[2][4] = {};
        #pragma unroll
        for (int mi = 0; mi < 2; ++mi)
            #pragma unroll
            for (int ds = 0; ds < 4; ++ds) {
                int r = wave * 32 + mi * 16 + (lane & 15);
                bf16x8 af = *(const bf16x8*)((const char*)Qlds + swz(r, 256, ds * 64 + (lane >> 4) * 16));
                #pragma unroll
                for (int ni = 0; ni < 4; ++ni)
                    st[mi][ni] = mfma16(af, kfr[ni][ds], st[mi][ni]);
            }
        // online per-column update (col k = lane&15 within ni block)
        #pragma unroll
        for (int ni = 0; ni < 4; ++ni) {
            float cm = -1e30f;
            #pragma unroll
            for (int mi = 0; mi < 2; ++mi)
                #pragma unroll
                for (int j = 0; j < 4; ++j) cm = fmaxf(cm, st[mi][ni][j]);
            cm *= SC2;
            cm = fmaxf(cm, __shfl_xor(cm, 16, 64));
            cm = fmaxf(cm, __shfl_xor(cm, 32, 64));
            float mnew = fmaxf(mrun[ni], cm);
            float p = 0.f;
            #pragma unroll
            for (int mi = 0; mi < 2; ++mi)
                #pragma unroll
                for (int j = 0; j < 4; ++j)
                    p += EXP2F(st[mi][ni][j] * SC2 - mnew);
            p += __shfl_xor(p, 16, 64);
            p += __shfl_xor(p, 32, 64);
            lrun[ni] = lrun[ni] * EXP2F(mrun[ni] - mnew) + p;
            mrun[ni] = mnew;
        }
    }
    // cross-wave combine (each wave covered a disjoint q subset)
    __syncthreads();
    float* redm = (float*)Klds;       // reuse: 4*64 floats
    float* redl = redm + 256;
    if (lane < 16) {
        #pragma unroll
        for (int ni = 0; ni < 4; ++ni) {
            redm[wave * 64 + ni * 16 + lane] = mrun[ni];
            redl[wave * 64 + ni * 16 + lane] = lrun[ni];
        }
    }
    __syncthreads();
    if (tid < 64) {
        float m0 = redm[tid], m1 = redm[64 + tid], m2v = redm[128 + tid], m3 = redm[192 + tid];
        float mt = fmaxf(fmaxf(m0, m1), fmaxf(m2v, m3));
        float lt = redl[tid]       * EXP2F(m0 - mt) + redl[64 + tid]  * EXP2F(m1 - mt)
                 + redl[128 + tid] * EXP2F(m2v - mt) + redl[192 + tid] * EXP2F(m3 - mt);
        Mpart[((size_t)qs * B_ + b) * L_ + k0 + tid] = mt;
        Lpart[((size_t)qs * B_ + b) * L_ + k0 + tid] = lt;
    }
}

// ---------------------------------------------------------------------------
// Kernel B2: combine QS partial stats -> M2, Lsum.  grid (B*L/256), block 256
// ---------------------------------------------------------------------------
__global__ __launch_bounds__(256) void comb_kernel(
    const float* __restrict__ Mpart, const float* __restrict__ Lpart,
    float* __restrict__ M2, float* __restrict__ Lsum)
{
    const size_t i = (size_t)blockIdx.x * 256 + threadIdx.x;
    const size_t N = (size_t)B_ * L_;
    float m = -1e30f;
    #pragma unroll
    for (int qs = 0; qs < QS; ++qs) m = fmaxf(m, Mpart[qs * N + i]);
    float l = 0.f;
    #pragma unroll
    for (int qs = 0; qs < QS; ++qs) l += Lpart[qs * N + i] * EXP2F(Mpart[qs * N + i] - m);
    M2[i] = m;
    Lsum[i] = l;
}

// ---------------------------------------------------------------------------
// Kernel C: VT[b][v][k] = V[b][k][v] / l[b][k]   (transpose + scale)
// grid (64, 2, 4), block 256
// ---------------------------------------------------------------------------
__global__ __launch_bounds__(256) void vt_kernel(
    const bf16_t* __restrict__ V, const float* __restrict__ Lsum, bf16_t* __restrict__ VT)
{
    const int b = blockIdx.z, v0 = blockIdx.y * 64, k0 = blockIdx.x * 64;
    __shared__ bf16_t tile[64][72];
    const int tid = threadIdx.x;
    const bf16_t* Vb = V + ((size_t)b * L_ + k0) * DH + v0;
    #pragma unroll
    for (int it = 0; it < 2; ++it) {
        int id = it * 256 + tid;
        int r = id >> 3, s = id & 7;
        bf16x8 x = *(const bf16x8*)&Vb[(size_t)r * DH + s * 8];
        *(bf16x8*)&tile[r][s * 8] = x;
    }
    __syncthreads();
    const int lane = tid & 63, wave = tid >> 6;
    float rl = 1.0f / Lsum[(size_t)b * L_ + k0 + lane];
    bf16_t* VTb = VT + ((size_t)b * DH + v0) * L_ + k0;
    #pragma unroll
    for (int i = 0; i < 16; ++i) {
        int v = wave * 16 + i;
        float x = (float)tile[lane][v];
        VTb[(size_t)v * L_ + lane] = (__bf16)(x * rl);
    }
}

// ---------------------------------------------------------------------------
// Kernel D: H[q,v] += sum_{k in range} exp2(s*SC2 - m2[k]) * VT[v][k]
// grid (64, B, KS), block 256 (4 waves).  q-block 64, k-range L/KS, chunks 64.
// Partial k-sums are additive (1/l folded into VT) -> fp32 atomicAdd to out.
// ---------------------------------------------------------------------------
__global__ __launch_bounds__(256) void pv_kernel(
    const bf16_t* __restrict__ Q, const bf16_t* __restrict__ K,
    const bf16_t* __restrict__ VT, const float* __restrict__ M2,
    float* __restrict__ out)
{
    const int b = blockIdx.y;
    const int q0 = blockIdx.x * 64;
    const int tid = threadIdx.x, lane = tid & 63, wave = tid >> 6;

    __shared__ bf16_t QPlds[64 * 128];   // 16 KB: Q staging, then P tile (first 8 KB)
    __shared__ bf16_t Klds[64 * 128];    // 16 KB
    __shared__ bf16_t VTlds[128 * 64];   // 16 KB, rows 128 B

    const bf16_t* Qb = Q + ((size_t)b * L_ + q0) * DH;
    #pragma unroll
    for (int it = 0; it < 4; ++it) {
        int id = it * 256 + tid;
        int r = id >> 4, s = id & 15;
        bf16x8 x = *(const bf16x8*)&Qb[(size_t)r * DH + s * 8];
        *(bf16x8*)((char*)QPlds + swz(r, 256, s * 16)) = x;
    }
    __syncthreads();
    // resident Q fragments (B-operand of S^T): [ni = q 16-block][d-slice]
    bf16x8 qf[4][4];
    #pragma unroll
    for (int ni = 0; ni < 4; ++ni)
        #pragma unroll
        for (int ds = 0; ds < 4; ++ds) {
            int r = ni * 16 + (lane & 15);
            qf[ni][ds] = *(const bf16x8*)((const char*)QPlds + swz(r, 256, ds * 64 + (lane >> 4) * 16));
        }

    f32x4 acc[4][2] = {};
    const float*  m2b = M2 + (size_t)b * L_;
    const bf16_t* Kb  = K  + (size_t)b * L_ * DH;
    const bf16_t* VTb = VT + (size_t)b * DH * L_;
    bf16_t* Plds = QPlds;                // alias: safe after qf loads + barrier

    const int kbase = blockIdx.z * (L_ / KS);
    for (int kc = kbase; kc < kbase + L_ / KS; kc += 64) {
        __syncthreads();
        // stage K chunk [64 k][128 d]
        #pragma unroll
        for (int it = 0; it < 4; ++it) {
            int id = it * 256 + tid;
            int r = id >> 4, s = id & 15;
            bf16x8 x = *(const bf16x8*)&Kb[(size_t)(kc + r) * DH + s * 8];
            *(bf16x8*)((char*)Klds + swz(r, 256, s * 16)) = x;
        }
        // stage VT chunk [128 v][64 k]
        #pragma unroll
        for (int it = 0; it < 4; ++it) {
            int id = it * 256 + tid;
            int r = id >> 3, s = id & 7;
            bf16x8 x = *(const bf16x8*)&VTb[(size_t)r * L_ + kc + s * 8];
            *(bf16x8*)((char*)VTlds + swz(r, 128, s * 16)) = x;
        }
        __syncthreads();
        // S^T tile: wave w owns k rows [w*16, w*16+16), all 64 q
        f32x4 st[4] = {};
        #pragma unroll
        for (int ds = 0; ds < 4; ++ds) {
            int r = wave * 16 + (lane & 15);
            bf16x8 kf = *(const bf16x8*)((const char*)Klds + swz(r, 256, ds * 64 + (lane >> 4) * 16));
            #pragma unroll
            for (int ni = 0; ni < 4; ++ni)
                st[ni] = mfma16(kf, qf[ni][ds], st[ni]);
        }
        // P = exp2(s*SC2 - m2[k]), write bf16 to Plds (lane's 4 k contiguous)
        float4 mv = *(const float4*)&m2b[kc + wave * 16 + (lane >> 4) * 4];
        #pragma unroll
        for (int ni = 0; ni < 4; ++ni) {
            bf16x4 pk;
            pk[0] = (__bf16)EXP2F(st[ni][0] * SC2 - mv.x);
            pk[1] = (__bf16)EXP2F(st[ni][1] * SC2 - mv.y);
            pk[2] = (__bf16)EXP2F(st[ni][2] * SC2 - mv.z);
            pk[3] = (__bf16)EXP2F(st[ni][3] * SC2 - mv.w);
            int q = ni * 16 + (lane & 15);
            int colbyte = wave * 32 + (lane >> 4) * 8;
            *(bf16x4*)((char*)Plds + swz(q, 128, colbyte)) = pk;
        }
        __syncthreads();
        // PV: wave w owns v strip [w*32, w*32+32)
        #pragma unroll
        for (int ks = 0; ks < 2; ++ks) {
            bf16x8 pf[4], vf[2];
            #pragma unroll
            for (int mi = 0; mi < 4; ++mi) {
                int q = mi * 16 + (lane & 15);
                pf[mi] = *(const bf16x8*)((const char*)Plds + swz(q, 128, ks * 64 + (lane >> 4) * 16));
            }
            #pragma unroll
            for (int ni = 0; ni < 2; ++ni) {
                int v = wave * 32 + ni * 16 + (lane & 15);
                vf[ni] = *(const bf16x8*)((const char*)VTlds + swz(v, 128, ks * 64 + (lane >> 4) * 16));
            }
            #pragma unroll
            for (int mi = 0; mi < 4; ++mi)
                #pragma unroll
                for (int ni = 0; ni < 2; ++ni)
                    acc[mi][ni] = mfma16(pf[mi], vf[ni], acc[mi][ni]);
        }
    }
    // epilogue: fp32 atomic accumulate (KS blocks contribute per output)
    #pragma unroll
    for (int mi = 0; mi < 4; ++mi)
        #pragma unroll
        for (int ni = 0; ni < 2; ++ni)
            #pragma unroll
            for (int j = 0; j < 4; ++j) {
                int q = q0 + mi * 16 + (lane >> 4) * 4 + j;
                int v = wave * 32 + ni * 16 + (lane & 15);
                atomicAdd(&out[((size_t)b * L_ + q) * DH + v], acc[mi][ni][j]);
            }
}

// ---------------------------------------------------------------------------
extern "C" void kernel_launch(void* const* d_in, const int* in_sizes, int n_in,
                              void* d_out, int out_size, void* d_ws, size_t ws_size,
                              hipStream_t stream)
{
    const float* inq = (const float*)d_in[0];
    const float* ink = (const float*)d_in[1];
    const float* inv = (const float*)d_in[2];
    const float* Wq  = (const float*)d_in[3];
    const float* bq  = (const float*)d_in[4];
    const float* Wk  = (const float*)d_in[5];
    const float* bk  = (const float*)d_in[6];
    const float* Wv  = (const float*)d_in[7];
    const float* bv  = (const float*)d_in[8];
    float* out = (float*)d_out;

    const size_t nQKV = (size_t)B_ * L_ * DH;   // 2,097,152 elements
    const size_t nBL  = (size_t)B_ * L_;
    char* ws = (char*)d_ws;
    bf16_t* Q  = (bf16_t*)ws;
    bf16_t* K  = Q + nQKV;
    bf16_t* V  = K + nQKV;
    bf16_t* VT = V + nQKV;
    float*  M2    = (float*)(VT + nQKV);
    float*  Lsum  = M2 + nBL;
    float*  Mpart = Lsum + nBL;          // QS * B*L
    float*  Lpart = Mpart + QS * nBL;    // QS * B*L
    // Wb (3*128*1024 bf16 = 768 KB) aliases the VT region: Wb is only live
    // during wcvt+proj; VT is written by vt_kernel strictly after proj.
    bf16_t* Wbuf = VT;

    hipMemsetAsync(out, 0, nQKV * sizeof(float), stream);
    wcvt_kernel<<<dim3(192), 256, 0, stream>>>(Wq, Wk, Wv, Wbuf);
    proj_kernel<<<dim3(256, 3), 256, 0, stream>>>(inq, ink, inv, Wbuf, bq, bk, bv, Q, K, V);
    stats_kernel<<<dim3(L_ / 64, B_, QS), 256, 0, stream>>>(Q, K, Mpart, Lpart);
    comb_kernel<<<dim3(nBL / 256), 256, 0, stream>>>(Mpart, Lpart, M2, Lsum);
    vt_kernel<<<dim3(L_ / 64, DH / 64, B_), 256, 0, stream>>>(V, Lsum, VT);
    pv_kernel<<<dim3(L_ / 64, B_, KS), 256, 0, stream>>>(Q, K, VT, M2, out);
}